// Round 15
// baseline (346.600 us; speedup 1.0000x reference)
//
#include <hip/hip_runtime.h>
#include <hip/hip_bf16.h>
#include <hip/hip_fp16.h>
#include <cstddef>

// Problem constants
// B=4, H=W=64, DIM=768, HEADS=12, HD=64, STRIDE=2, N=4097, pooled tokens=1025
#define NTOK 4097
#define NPOOL 1025
#define DIMC 768

typedef short  s16x8 __attribute__((ext_vector_type(8)));
typedef _Float16 f16x8 __attribute__((ext_vector_type(8)));
typedef float  f32x4 __attribute__((ext_vector_type(4)));
typedef unsigned short u16x8 __attribute__((ext_vector_type(8)));

static __device__ inline unsigned short f2bf(float x) {
    __hip_bfloat16 h = __float2bfloat16(x);
    return *reinterpret_cast<unsigned short*>(&h);
}
static __device__ inline float bf2f(unsigned short u) {
    __hip_bfloat16 h;
    *reinterpret_cast<unsigned short*>(&h) = u;
    return __bfloat162float(h);
}
static __device__ inline unsigned short f2h(float x) {
    __half h = __float2half(x);
    return *reinterpret_cast<unsigned short*>(&h);
}
static __device__ inline float h2f(unsigned short u) {
    __half h;
    *reinterpret_cast<unsigned short*>(&h) = u;
    return __half2float(h);
}

#define GLDS(gp, lp) __builtin_amdgcn_global_load_lds(                        \
    (const __attribute__((address_space(1))) void*)(gp),                      \
    (__attribute__((address_space(3))) void*)(lp), 16, 0, 0)

// ---------------------------------------------------------------------------
// Pad + convert f32 [rows_valid][768] -> bf16 [rows_pad][768] (pad rows zero).
// ---------------------------------------------------------------------------
__global__ __launch_bounds__(256) void cvt_pad(const float* __restrict__ in,
                                               unsigned short* __restrict__ out,
                                               int rows_valid, int groups) {
    const int g = blockIdx.x * 256 + threadIdx.x;
    if (g >= groups) return;
    const int row = g / 96, off = (g - row * 96) * 8;
    u16x8 o;
    if (row < rows_valid) {
        const float4 v0 = *(const float4*)(in + (size_t)row * DIMC + off);
        const float4 v1 = *(const float4*)(in + (size_t)row * DIMC + off + 4);
        o[0] = f2bf(v0.x); o[1] = f2bf(v0.y); o[2] = f2bf(v0.z); o[3] = f2bf(v0.w);
        o[4] = f2bf(v1.x); o[5] = f2bf(v1.y); o[6] = f2bf(v1.z); o[7] = f2bf(v1.w);
    } else {
        o = (u16x8){0, 0, 0, 0, 0, 0, 0, 0};
    }
    *(u16x8*)(out + (size_t)g * 8) = o;
}

// ---------------------------------------------------------------------------
// Transpose + convert: in f32 [R][C] -> out bf16 [C][R]. R,C % 32 == 0.
// ---------------------------------------------------------------------------
__global__ __launch_bounds__(256) void transpose_cvt(const float* __restrict__ in,
                                                     unsigned short* __restrict__ out,
                                                     int R, int C) {
    __shared__ float t[32][33];
    const int tx = threadIdx.x & 31, ty = threadIdx.x >> 5;   // ty 0..7
    const int r0 = blockIdx.y * 32, c0 = blockIdx.x * 32;
#pragma unroll
    for (int i = 0; i < 32; i += 8)
        t[ty + i][tx] = in[(size_t)(r0 + ty + i) * C + c0 + tx];
    __syncthreads();
#pragma unroll
    for (int i = 0; i < 32; i += 8)
        out[(size_t)(c0 + ty + i) * R + r0 + tx] = f2bf(t[tx][ty + i]);
}

// ---------------------------------------------------------------------------
// 256x256 bf16 GEMM, BK=32, 4-buffer counted-vmcnt pipeline (unchanged).
// ---------------------------------------------------------------------------
__global__ __launch_bounds__(512, 2) void gemm256_bf16(
    const unsigned short* __restrict__ A,
    const unsigned short* __restrict__ Bt,
    unsigned short* __restrict__ C,
    int M) {
    __shared__ short lds[4][2][8192];   // [buf][A/B][p*64 + b'*8 + s]
    const int tid = threadIdx.x, w = tid >> 6, lane = tid & 63;
    const int frow = lane & 15;

    const unsigned nwg = gridDim.x * gridDim.y;
    const unsigned lin = blockIdx.y * gridDim.x + blockIdx.x;
    const unsigned qq = nwg >> 3, rr = nwg & 7;
    const unsigned xcd = lin & 7, off = lin >> 3;
    const unsigned lin2 = (xcd < rr ? xcd * (qq + 1) : rr * (qq + 1) + (xcd - rr) * qq) + off;
    const int bx = lin2 % gridDim.x, by = lin2 / gridDim.x;
    const int bm = by * 256, bn = bx * 256;

    const int wm = w >> 2, wn = w & 3;

    const int p0s = w * 8 + (lane >> 3);
    const int bA = (lane & 7) ^ (p0s & 7);
    const int r0s = 2 * p0s + (bA >> 2);
    const int cbs = bA & 3;
    const unsigned short* aSrc = A + (size_t)(bm + r0s) * 768 + cbs * 8;
    const unsigned short* bSrc = Bt + (size_t)(bn + r0s) * 768 + cbs * 8;

#define STAGE256(buf_, t_) do {                                               \
    const unsigned short* a_ = aSrc + (size_t)(t_) * 32;                      \
    const unsigned short* b_ = bSrc + (size_t)(t_) * 32;                      \
    GLDS(a_,             &lds[buf_][0][w * 512]);                             \
    GLDS(a_ + 128 * 768, &lds[buf_][0][w * 512 + 4096]);                      \
    GLDS(b_,             &lds[buf_][1][w * 512]);                             \
    GLDS(b_ + 128 * 768, &lds[buf_][1][w * 512 + 4096]);                      \
} while (0)

    f32x4 acc[8][4];
#pragma unroll
    for (int m = 0; m < 8; ++m)
#pragma unroll
        for (int n = 0; n < 4; ++n) acc[m][n] = (f32x4){0.f, 0.f, 0.f, 0.f};

    const int bp = (((frow & 1) << 2) | (lane >> 4)) ^ (frow >> 1);
    const int pA0 = wm * 64 + (frow >> 1);
    const int pB0 = wn * 32 + (frow >> 1);

    STAGE256(0, 0);
    STAGE256(1, 1);
    asm volatile("s_waitcnt vmcnt(4)" ::: "memory");
    __builtin_amdgcn_s_barrier();

    for (int t = 0; t < 24; ++t) {
        const int cur = t & 3;
        s16x8 af[8], bf[4];
#pragma unroll
        for (int i = 0; i < 8; ++i)
            af[i] = *(const s16x8*)&lds[cur][0][(pA0 + i * 8) * 64 + bp * 8];
#pragma unroll
        for (int i = 0; i < 4; ++i)
            bf[i] = *(const s16x8*)&lds[cur][1][(pB0 + i * 8) * 64 + bp * 8];
        if (t + 2 < 24) STAGE256((t + 2) & 3, t + 2);
        asm volatile("s_waitcnt lgkmcnt(0)" ::: "memory");
        __builtin_amdgcn_sched_barrier(0);
        __builtin_amdgcn_s_setprio(1);
#pragma unroll
        for (int i = 0; i < 8; ++i)
#pragma unroll
            for (int nf = 0; nf < 4; ++nf)
                acc[i][nf] = __builtin_amdgcn_mfma_f32_16x16x32_bf16(
                    bf[nf], af[i], acc[i][nf], 0, 0, 0);
        __builtin_amdgcn_s_setprio(0);
        __builtin_amdgcn_sched_barrier(0);
        if (t == 22) asm volatile("s_waitcnt vmcnt(0)" ::: "memory");
        else         asm volatile("s_waitcnt vmcnt(4)" ::: "memory");
        __builtin_amdgcn_s_barrier();
    }
#undef STAGE256

    const int mrow0 = bm + wm * 128 + frow;
    const int cb0 = bn + wn * 64 + (lane >> 4) * 4;
#pragma unroll
    for (int m = 0; m < 8; ++m) {
        const int row = mrow0 + m * 16;
        if (row >= M) continue;
#pragma unroll
        for (int n = 0; n < 4; ++n) {
            const int col = cb0 + n * 16;
            const f32x4 v = acc[m][n];
            unsigned int lo = f2bf(v[0]) | ((unsigned int)f2bf(v[1]) << 16);
            unsigned int hi = f2bf(v[2]) | ((unsigned int)f2bf(v[3]) << 16);
            *(uint2*)&C[(size_t)row * 2304 + col] = make_uint2(lo, hi);
        }
    }
}

// ---------------------------------------------------------------------------
// bf16 MFMA GEMM (128² 2-phase) — used for the small proj GEMM.
// ---------------------------------------------------------------------------
static __device__ inline void stage_tiles(const unsigned short* aG,
                                          const unsigned short* bG,
                                          short* aL, short* bL, int w, int K) {
    short* a = aL + w * 1024;
    short* b = bL + w * 1024;
    GLDS(aG, a); GLDS(aG + 16 * (size_t)K, a + 512);
    GLDS(bG, b); GLDS(bG + 16 * (size_t)K, b + 512);
}

static __device__ inline void compute_tile(const short* As_, const short* Bs_,
                                           int ar, int br, int ko,
                                           f32x4 acc[4][4]) {
    s16x8 af[4], bf[4];
#pragma unroll
    for (int m = 0; m < 4; ++m)
        af[m] = *(const s16x8*)&As_[(ar + m * 16) * 32 + ko];
#pragma unroll
    for (int n = 0; n < 4; ++n)
        bf[n] = *(const s16x8*)&Bs_[(br + n * 16) * 32 + ko];
#pragma unroll
    for (int m = 0; m < 4; ++m)
#pragma unroll
        for (int n = 0; n < 4; ++n)
            acc[m][n] = __builtin_amdgcn_mfma_f32_16x16x32_bf16(bf[n], af[m], acc[m][n], 0, 0, 0);
}

__global__ __launch_bounds__(256) void gemm_bf16(const unsigned short* __restrict__ A,
                                                 const unsigned short* __restrict__ Bt,
                                                 const float* __restrict__ bias,
                                                 void* __restrict__ Cv,
                                                 int M, int N, int K, int out_bf) {
    __shared__ __align__(16) short As0[4096], Bs0[4096], As1[4096], Bs1[4096];
    const int tid = threadIdx.x;
    const int w = tid >> 6, lane = tid & 63;

    const unsigned nwg = gridDim.x * gridDim.y;
    const unsigned lin = blockIdx.y * gridDim.x + blockIdx.x;
    const unsigned qq = nwg >> 3, rr = nwg & 7;
    const unsigned xcd = lin & 7, off = lin >> 3;
    const unsigned lin2 = (xcd < rr ? xcd * (qq + 1) : rr * (qq + 1) + (xcd - rr) * qq) + off;
    const int bx = lin2 % gridDim.x, by = lin2 / gridDim.x;
    const int bm = by * 128, bn = bx * 128;

    const int sr = lane >> 2, sc8 = (lane & 3) * 8;
    const unsigned short* aG = A + (size_t)(bm + w * 32 + sr) * K + sc8;
    const unsigned short* bG = Bt + (size_t)(bn + w * 32 + sr) * K + sc8;

    f32x4 acc[4][4];
#pragma unroll
    for (int m = 0; m < 4; ++m)
#pragma unroll
        for (int n = 0; n < 4; ++n) acc[m][n] = (f32x4){0.f, 0.f, 0.f, 0.f};

    const int wr = w >> 1, wc = w & 1;
    const int ar = wr * 64 + (lane & 15);
    const int br = wc * 64 + (lane & 15);
    const int ko = (lane >> 4) * 8;

    stage_tiles(aG, bG, As0, Bs0, w, K);
    aG += 32; bG += 32;
    const int T = K >> 5;
    for (int t = 0; t < T; ++t) {
        __syncthreads();
        const bool last = (t + 1 == T);
        if ((t & 1) == 0) {
            if (!last) { stage_tiles(aG, bG, As1, Bs1, w, K); aG += 32; bG += 32; }
            compute_tile(As0, Bs0, ar, br, ko, acc);
        } else {
            if (!last) { stage_tiles(aG, bG, As0, Bs0, w, K); aG += 32; bG += 32; }
            compute_tile(As1, Bs1, ar, br, ko, acc);
        }
    }

    const int mrow0 = bm + wr * 64 + (lane & 15);
    const int cb0 = bn + wc * 64 + (lane >> 4) * 4;
    if (out_bf) {
        unsigned short* C = (unsigned short*)Cv;
#pragma unroll
        for (int m = 0; m < 4; ++m) {
            const int row = mrow0 + m * 16;
            if (row >= M) continue;
#pragma unroll
            for (int n = 0; n < 4; ++n) {
                const int col = cb0 + n * 16;
                const f32x4 v = acc[m][n];
                unsigned int lo = f2bf(v[0]) | ((unsigned int)f2bf(v[1]) << 16);
                unsigned int hi = f2bf(v[2]) | ((unsigned int)f2bf(v[3]) << 16);
                *(uint2*)&C[(size_t)row * N + col] = make_uint2(lo, hi);
            }
        }
    } else {
        float* C = (float*)Cv;
        f32x4 bv[4];
#pragma unroll
        for (int n = 0; n < 4; ++n)
            bv[n] = bias ? *(const f32x4*)(bias + cb0 + n * 16)
                         : (f32x4){0.f, 0.f, 0.f, 0.f};
#pragma unroll
        for (int m = 0; m < 4; ++m) {
            const int row = mrow0 + m * 16;
            if (row >= M) continue;
#pragma unroll
            for (int n = 0; n < 4; ++n) {
                const int col = cb0 + n * 16;
                f32x4 v = acc[m][n] + bv[n];
                *(f32x4*)&C[(size_t)row * N + col] = v;
            }
        }
    }
}

// ---------------------------------------------------------------------------
// Pool v3 (tiled): block = (8x8 output tile, one 64-ch head slice db, which,
// b). Stages the 17x17 input patch for this channel slice in LDS (37 KB,
// coalesced 128-B pixel rows), then each thread computes 4 outputs x 4 ch
// from LDS (reuse ~2.25x). LN over 64 ch = in-thread 4 + 16-lane shuffle.
// Tile 16 = cls token (LN only, threads 0..15).
// ---------------------------------------------------------------------------
__global__ __launch_bounds__(256) void pool_ln_tiled(
    const unsigned short* __restrict__ qkv,
    const float* __restrict__ dwq, const float* __restrict__ dwk, const float* __restrict__ dwv,
    const float* __restrict__ gq, const float* __restrict__ bq,
    const float* __restrict__ gk, const float* __restrict__ bk,
    const float* __restrict__ gv, const float* __restrict__ bv,
    float* __restrict__ qp, unsigned short* __restrict__ qbf,
    unsigned short* __restrict__ kbf, unsigned short* __restrict__ vtf16) {
    __shared__ __align__(16) unsigned short in_s[289 * 64];
    const int tile = blockIdx.x;          // 0..15 spatial, 16 = cls
    const int which = blockIdx.y / 12, db = blockIdx.y % 12;
    const int bi = blockIdx.z;
    const float* wt  = which == 0 ? dwq : which == 1 ? dwk : dwv;
    const float* gam = which == 0 ? gq  : which == 1 ? gk  : gv;
    const float* bet = which == 0 ? bq  : which == 1 ? bk  : bv;
    const int tid = threadIdx.x;
    const int ci0 = (tid & 15) * 4;
    const int d0 = db * 64 + ci0;
    const size_t base = (size_t)bi * NTOK * 2304 + (size_t)which * DIMC;

    if (tile == 16) {                     // cls token
        if (tid < 16) {
            float v0 = bf2f(qkv[base + d0]);
            float v1 = bf2f(qkv[base + d0 + 1]);
            float v2 = bf2f(qkv[base + d0 + 2]);
            float v3 = bf2f(qkv[base + d0 + 3]);
            float s = v0 + v1 + v2 + v3;
#pragma unroll
            for (int o = 8; o > 0; o >>= 1) s += __shfl_xor(s, o);
            const float mu = s * (1.f / 64.f);
            const float e0 = v0 - mu, e1 = v1 - mu, e2 = v2 - mu, e3 = v3 - mu;
            float s2 = e0 * e0 + e1 * e1 + e2 * e2 + e3 * e3;
#pragma unroll
            for (int o = 8; o > 0; o >>= 1) s2 += __shfl_xor(s2, o);
            const float inv = rsqrtf(s2 * (1.f / 64.f) + 1e-3f);
            const f32x4 gv4 = *(const f32x4*)(gam + ci0);
            const f32x4 bv4 = *(const f32x4*)(bet + ci0);
            f32x4 res;
            res[0] = e0 * inv * gv4[0] + bv4[0];
            res[1] = e1 * inv * gv4[1] + bv4[1];
            res[2] = e2 * inv * gv4[2] + bv4[2];
            res[3] = e3 * inv * gv4[3] + bv4[3];
            const size_t bh = (size_t)(bi * 12 + db);   // h = db, tok = 0
            const unsigned int lo = f2bf(res[0]) | ((unsigned int)f2bf(res[1]) << 16);
            const unsigned int hi = f2bf(res[2]) | ((unsigned int)f2bf(res[3]) << 16);
            if (which == 0) {
                *(f32x4*)&qp[(bh * NPOOL) * 64 + ci0] = res;
                *(uint2*)&qbf[(bh * 1040) * 64 + ci0] = make_uint2(lo, hi);
            } else if (which == 1) {
                *(uint2*)&kbf[(bh * 1056) * 64 + ci0] = make_uint2(lo, hi);
            } else {
#pragma unroll
                for (int j = 0; j < 4; ++j)
                    vtf16[(bh * 64 + ci0 + j) * 1056] = f2h(res[j]);
            }
        }
        return;
    }

    // ---- stage 17x17 input patch (this channel slice) into LDS ----
    const int ty = tile >> 2, tx = tile & 3;
    const int ih0 = ty * 16, iw0 = tx * 16;
#pragma unroll
    for (int i = 0; i < 19; ++i) {
        const int c = tid + i * 256;
        if (c < 4624) {                  // 289 pixels x 16 chunks
            const int p = c >> 4, cc = (c & 15) * 4;
            const int ph = p / 17, pw = p - ph * 17;
            const int ih = ih0 + ph, iw = iw0 + pw;
            ushort4 ld = make_ushort4(0, 0, 0, 0);
            if (ih < 64 && iw < 64) {
                const int pix = ih * 64 + iw;
                const int t6 = pix * 12 + db;
                const int l = t6 & 4095, hin = t6 >> 12;
                ld = *(const ushort4*)(qkv + base + (size_t)(1 + l) * 2304 + hin * 64 + cc);
            }
            *(ushort4*)&in_s[p * 64 + cc] = ld;
        }
    }
    __syncthreads();

    // ---- weights for this channel quad ----
    f32x4 wv[9];
#pragma unroll
    for (int k9 = 0; k9 < 9; ++k9)
        wv[k9] = *(const f32x4*)(wt + k9 * DIMC + d0);

    // ---- each thread: 4 outputs x 4 channels ----
#pragma unroll
    for (int i = 0; i < 4; ++i) {
        const int og = (tid >> 4) + i * 16;       // 0..63 within 8x8 tile
        const int oy = og >> 3, ox = og & 7;
        float a0 = 0.f, a1 = 0.f, a2 = 0.f, a3 = 0.f;
#pragma unroll
        for (int kh = 0; kh < 3; ++kh)
#pragma unroll
            for (int kw = 0; kw < 3; ++kw) {
                const int p = (oy * 2 + kh) * 17 + (ox * 2 + kw);
                const ushort4 pv = *(const ushort4*)&in_s[p * 64 + ci0];
                const f32x4 wvv = wv[kh * 3 + kw];
                a0 += bf2f(pv.x) * wvv[0];
                a1 += bf2f(pv.y) * wvv[1];
                a2 += bf2f(pv.z) * wvv[2];
                a3 += bf2f(pv.w) * wvv[3];
            }
        // LayerNorm over the 16-lane group (64 channels)
        float s = a0 + a1 + a2 + a3;
#pragma unroll
        for (int o = 8; o > 0; o >>= 1) s += __shfl_xor(s, o);
        const float mu = s * (1.f / 64.f);
        const float e0 = a0 - mu, e1 = a1 - mu, e2 = a2 - mu, e3 = a3 - mu;
        float s2 = e0 * e0 + e1 * e1 + e2 * e2 + e3 * e3;
#pragma unroll
        for (int o = 8; o > 0; o >>= 1) s2 += __shfl_xor(s2, o);
        const float inv = rsqrtf(s2 * (1.f / 64.f) + 1e-3f);
        const f32x4 gv4 = *(const f32x4*)(gam + ci0);
        const f32x4 bv4 = *(const f32x4*)(bet + ci0);
        f32x4 res;
        res[0] = e0 * inv * gv4[0] + bv4[0];
        res[1] = e1 * inv * gv4[1] + bv4[1];
        res[2] = e2 * inv * gv4[2] + bv4[2];
        res[3] = e3 * inv * gv4[3] + bv4[3];

        const int pos = (ty * 8 + oy) * 32 + (tx * 8 + ox);
        const int idx = pos * 12 + db;
        const int h = idx >> 10, tok = 1 + (idx & 1023);
        const size_t bh = (size_t)(bi * 12 + h);
        const unsigned int lo = f2bf(res[0]) | ((unsigned int)f2bf(res[1]) << 16);
        const unsigned int hi = f2bf(res[2]) | ((unsigned int)f2bf(res[3]) << 16);
        if (which == 0) {
            *(f32x4*)&qp[(bh * NPOOL + tok) * 64 + ci0] = res;
            *(uint2*)&qbf[(bh * 1040 + tok) * 64 + ci0] = make_uint2(lo, hi);
        } else if (which == 1) {
            *(uint2*)&kbf[(bh * 1056 + tok) * 64 + ci0] = make_uint2(lo, hi);
        } else {
#pragma unroll
            for (int j = 0; j < 4; ++j)
                vtf16[(bh * 64 + ci0 + j) * 1056 + tok] = f2h(res[j]);
        }
    }
}

// ---------------------------------------------------------------------------
// rel tables
// ---------------------------------------------------------------------------
__global__ __launch_bounds__(256) void rel_kernel(const float* __restrict__ qp,
                                                  const float* __restrict__ rph,
                                                  const float* __restrict__ rpw,
                                                  float* __restrict__ relH,
                                                  float* __restrict__ relW) {
    __shared__ float qs[4][64];
    const int wave = threadIdx.x >> 6, lane = threadIdx.x & 63;
    const int r = blockIdx.x * 4 + wave;
    const int bh = r >> 10, pos = r & 1023;
    const int qh = pos >> 5, qw = pos & 31;
    qs[wave][lane] = qp[((size_t)bh * NPOOL + 1 + pos) * 64 + lane];
    __syncthreads();
    const int kj = lane & 31;
    const float* tab = (lane < 32) ? (rph + (qh - kj + 31) * 64)
                                   : (rpw + (qw - kj + 31) * 64);
    float acc = 0.f;
#pragma unroll
    for (int c = 0; c < 64; ++c) acc += qs[wave][c] * tab[c];
    if (lane < 32) relH[(size_t)r * 32 + kj] = acc;
    else           relW[(size_t)r * 32 + kj] = acc;
}

// ---------------------------------------------------------------------------
// MFMA attention, 8 waves, f16 logits/P tile (45 KB LDS, 3 blocks/CU).
// (round-13 version: fused-max pass1, plain pass3 — prefetch reverted)
// ---------------------------------------------------------------------------
#define LSTR16 1088
#define LI16(q, k) ((q) * LSTR16 + (((((k) >> 3) ^ ((q) & 7)) << 3) | ((k) & 7)))
__global__ __launch_bounds__(512) void attn_mfma(
    const unsigned short* __restrict__ qbf, const unsigned short* __restrict__ kbf,
    const unsigned short* __restrict__ vtf16, const float* __restrict__ qpf,
    const float* __restrict__ relH, const float* __restrict__ relW,
    unsigned short* __restrict__ outbf) {
    __shared__ __align__(16) unsigned short logits_s[16 * LSTR16];
    __shared__ float relh_s[32][17];
    __shared__ float relw_s[32][17];
    __shared__ __align__(16) float partial_s[4][16][20];
    __shared__ float srow_s[16];
    __shared__ float wmax_s[8][16];
    const int bh = blockIdx.y, bi = bh / 12, hh = bh % 12;
    const int q0 = blockIdx.x * 16;
    const int tid = threadIdx.x, w = tid >> 6, lane = tid & 63;

    {
        const int qi = tid >> 5, j = tid & 31;
        const int qg = q0 + qi;
        float rh = 0.f, rw = 0.f;
        if (qg >= 1 && qg < NPOOL) {
            const size_t rb = ((size_t)bh * 1024 + (qg - 1)) * 32;
            rh = relH[rb + j]; rw = relW[rb + j];
        }
        relh_s[j][qi] = rh; relw_s[j][qi] = rw;
    }

    const int frow = lane & 15, fcol = (lane >> 4) * 8;
    const unsigned short* qrow_p = qbf + ((size_t)bh * 1040 + q0 + frow) * 64 + fcol;
    s16x8 aq0 = *(const s16x8*)qrow_p;
    s16x8 aq1 = *(const s16x8*)(qrow_p + 32);
    __syncthreads();

    // ---- pass 1: logits -> f16 tile, fused per-lane max ----
    const int qrow1 = frow, qg1 = q0 + qrow1;
    float lmax = -3.0e38f;
    for (int t = w; t < 66; t += 8) {
        const int k0 = t * 16;
        const unsigned short* kb = kbf + ((size_t)bh * 1056 + k0 + frow) * 64 + fcol;
        s16x8 b0 = *(const s16x8*)kb;
        s16x8 b1 = *(const s16x8*)(kb + 32);
        f32x4 s = (f32x4){0.f, 0.f, 0.f, 0.f};
        s = __builtin_amdgcn_mfma_f32_16x16x32_bf16(b0, aq0, s, 0, 0, 0);
        s = __builtin_amdgcn_mfma_f32_16x16x32_bf16(b1, aq1, s, 0, 0, 0);
        const int kbase = k0 + (lane >> 4) * 4;
        unsigned short hv[4];
#pragma unroll
        for (int r = 0; r < 4; ++r) {
            const int kcol = kbase + r;
            float v;
            if (kcol >= NPOOL) {
                v = -60000.0f;                        // f16-representable mask
            } else {
                v = s[r] * 0.125f;
                if (kcol >= 1 && qg1 >= 1)
                    v += relh_s[(kcol - 1) >> 5][qrow1] + relw_s[(kcol - 1) & 31][qrow1];
            }
            lmax = fmaxf(lmax, v);
            hv[r] = f2h(v);
        }
        const unsigned int lo = hv[0] | ((unsigned int)hv[1] << 16);
        const unsigned int hi = hv[2] | ((unsigned int)hv[3] << 16);
        *(uint2*)&logits_s[LI16(qrow1, kbase)] = make_uint2(lo, hi);
    }
    lmax = fmaxf(lmax, __shfl_xor(lmax, 16));
    lmax = fmaxf(lmax, __shfl_xor(lmax, 32));
    if (lane < 16) wmax_s[w][frow] = lmax;
    __syncthreads();

    // ---- pass 2: exp + sum in place (row max from wmax_s) ----
    for (int qi = w; qi < 16; qi += 8) {
        float m = wmax_s[0][qi];
#pragma unroll
        for (int w2 = 1; w2 < 8; ++w2) m = fmaxf(m, wmax_s[w2][qi]);
        float sum = 0.f;
#pragma unroll
        for (int i = 0; i < 9; ++i) {
            const int k = i * 128 + 2 * lane;
            if (k < 1056) {
                unsigned int* p = (unsigned int*)&logits_s[LI16(qi, k)];
                const unsigned int v = *p;
                const float p0 = __expf(h2f((unsigned short)v) - m);
                const float p1 = __expf(h2f((unsigned short)(v >> 16)) - m);
                *p = f2h(p0) | ((unsigned int)f2h(p1) << 16);
                sum += p0 + p1;
            }
        }
#pragma unroll
        for (int o = 32; o > 0; o >>= 1) sum += __shfl_xor(sum, o);
        if (lane == 0) srow_s[qi] = sum;
    }
    __syncthreads();

    // ---- pass 3: PV via f16 mfma, split (d-frag f) x (k-half h) ----
    const int f = w & 3, h = w >> 2;
    const int cstart = h ? 17 : 0, cend = h ? 33 : 17;
    const unsigned short* vrow = vtf16 + ((size_t)bh * 64 + f * 16 + frow) * 1056 + fcol;
    f32x4 acc = (f32x4){0.f, 0.f, 0.f, 0.f};
    for (int c = cstart; c < cend; ++c) {
        const int kb0 = c * 32 + fcol;
        f16x8 pa = *(const f16x8*)&logits_s[LI16(frow, kb0)];
        f16x8 vb = *(const f16x8*)(vrow + c * 32);
        acc = __builtin_amdgcn_mfma_f32_16x16x32_f16(vb, pa, acc, 0, 0, 0);
    }
    const int qrow = frow, qg = q0 + qrow;
    const int s0 = (lane >> 4) * 4;
    if (h == 1) {
        *(f32x4*)&partial_s[f][qrow][s0] = acc;
    }
    __syncthreads();
    if (h == 0 && qg < NPOOL) {
        const f32x4 other = *(const f32x4*)&partial_s[f][qrow][s0];
        const int d0 = f * 16 + s0;
        const float inv = 1.f / srow_s[qrow];
        const f32x4 res = *(const f32x4*)&qpf[((size_t)bh * NPOOL + qg) * 64 + d0];
        f32x4 o;
#pragma unroll
        for (int r = 0; r < 4; ++r) o[r] = (acc[r] + other[r]) * inv + res[r];
        const unsigned int lo = f2bf(o[0]) | ((unsigned int)f2bf(o[1]) << 16);
        const unsigned int hi = f2bf(o[2]) | ((unsigned int)f2bf(o[3]) << 16);
        *(uint2*)&outbf[((size_t)bi * NPOOL + qg) * DIMC + hh * 64 + d0] = make_uint2(lo, hi);
    }
}

// ---------------------------------------------------------------------------
extern "C" void kernel_launch(void* const* d_in, const int* in_sizes, int n_in,
                              void* d_out, int out_size, void* d_ws, size_t ws_size,
                              hipStream_t stream) {
    const float* x     = (const float*)d_in[0];
    const float* wqkv  = (const float*)d_in[1];
    const float* dwq   = (const float*)d_in[2];
    const float* dwk   = (const float*)d_in[3];
    const float* dwv   = (const float*)d_in[4];
    const float* gq    = (const float*)d_in[5];
    const float* bq    = (const float*)d_in[6];
    const float* gk    = (const float*)d_in[7];
    const float* bk    = (const float*)d_in[8];
    const float* gv    = (const float*)d_in[9];
    const float* bv    = (const float*)d_in[10];
    const float* rph   = (const float*)d_in[11];
    const float* rpw   = (const float*)d_in[12];
    const float* wproj = (const float*)d_in[13];
    const float* bproj = (const float*)d_in[14];
    float* out = (float*)d_out;
    float* ws_f = (float*)d_ws;

    // Workspace layout (f32 units): same as round 9/10.
    const size_t A = 37757952;
    unsigned short* qkv_bf = (unsigned short*)ws_f;
    float* qp = ws_f + A;
    unsigned short* qp_bf = (unsigned short*)(ws_f + A + 3148800);
    unsigned short* kp_bf = (unsigned short*)(ws_f + A + 4746240);
    unsigned short* vt_f16 = (unsigned short*)(ws_f + A + 6368256);
    unsigned short* wqkv_bf = (unsigned short*)(ws_f + A + 7990272);
    unsigned short* x_bf = (unsigned short*)qp;
    float* relH   = ws_f;
    float* relW   = ws_f + 1572864;
    unsigned short* outpre_bf = (unsigned short*)(ws_f + 3145728);  // 4224x768 u16
    unsigned short* wproj_bf  = (unsigned short*)(ws_f + 7916544);

    // 1) convert + pad A (to 16640 rows), transpose + convert B for qkv GEMM
    cvt_pad<<<(16640 * 96 + 255) / 256, 256, 0, stream>>>(x, x_bf, 16388, 16640 * 96);
    transpose_cvt<<<dim3(2304 / 32, 768 / 32), 256, 0, stream>>>(wqkv, wqkv_bf, 768, 2304);
    // 2) QKV GEMM (256², BK=32, 4-buffer counted-vmcnt) -> bf16
    gemm256_bf16<<<dim3(9, 65), 512, 0, stream>>>(x_bf, wqkv_bf, qkv_bf, 16388);
    // 3) conv-pool + LayerNorm (tiled, LDS-staged) -> qp f32, qp/kp bf16, V^T f16
    pool_ln_tiled<<<dim3(17, 36, 4), 256, 0, stream>>>(qkv_bf, dwq, dwk, dwv,
                                                       gq, bq, gk, bk, gv, bv,
                                                       qp, qp_bf, kp_bf, vt_f16);
    // 4) rel_h / rel_w tables
    rel_kernel<<<dim3(12288), 256, 0, stream>>>(qp, rph, rpw, relH, relW);
    // 5) MFMA attention (8 waves, fused-max softmax) -> outpre_bf bf16
    attn_mfma<<<dim3(65, 48), 512, 0, stream>>>(qp_bf, kp_bf, vt_f16, qp, relH, relW, outpre_bf);
    // 6) proj GEMM (128² bf16 MFMA): (4100 x 768) @ (768 x 768) + bias -> f32
    transpose_cvt<<<dim3(768 / 32, 768 / 32), 256, 0, stream>>>(wproj, wproj_bf, 768, 768);
    gemm_bf16<<<dim3(6, 33), 256, 0, stream>>>(outpre_bf, wproj_bf, bproj, out, 4100, 768, 768, 0);
}

// Round 16
// 266.805 us; speedup vs baseline: 1.2991x; 1.2991x over previous
//
#include <hip/hip_runtime.h>
#include <hip/hip_bf16.h>
#include <hip/hip_fp16.h>
#include <cstddef>

// Problem constants
// B=4, H=W=64, DIM=768, HEADS=12, HD=64, STRIDE=2, N=4097, pooled tokens=1025
#define NTOK 4097
#define NPOOL 1025
#define DIMC 768

typedef short  s16x8 __attribute__((ext_vector_type(8)));
typedef _Float16 f16x8 __attribute__((ext_vector_type(8)));
typedef float  f32x4 __attribute__((ext_vector_type(4)));
typedef unsigned short u16x8 __attribute__((ext_vector_type(8)));

static __device__ inline unsigned short f2bf(float x) {
    __hip_bfloat16 h = __float2bfloat16(x);
    return *reinterpret_cast<unsigned short*>(&h);
}
static __device__ inline float bf2f(unsigned short u) {
    __hip_bfloat16 h;
    *reinterpret_cast<unsigned short*>(&h) = u;
    return __bfloat162float(h);
}
static __device__ inline unsigned short f2h(float x) {
    __half h = __float2half(x);
    return *reinterpret_cast<unsigned short*>(&h);
}
static __device__ inline float h2f(unsigned short u) {
    __half h;
    *reinterpret_cast<unsigned short*>(&h) = u;
    return __half2float(h);
}

#define GLDS(gp, lp) __builtin_amdgcn_global_load_lds(                        \
    (const __attribute__((address_space(1))) void*)(gp),                      \
    (__attribute__((address_space(3))) void*)(lp), 16, 0, 0)

// ---------------------------------------------------------------------------
// Pad + convert f32 [rows_valid][768] -> bf16 [rows_pad][768] (pad rows zero).
// ---------------------------------------------------------------------------
__global__ __launch_bounds__(256) void cvt_pad(const float* __restrict__ in,
                                               unsigned short* __restrict__ out,
                                               int rows_valid, int groups) {
    const int g = blockIdx.x * 256 + threadIdx.x;
    if (g >= groups) return;
    const int row = g / 96, off = (g - row * 96) * 8;
    u16x8 o;
    if (row < rows_valid) {
        const float4 v0 = *(const float4*)(in + (size_t)row * DIMC + off);
        const float4 v1 = *(const float4*)(in + (size_t)row * DIMC + off + 4);
        o[0] = f2bf(v0.x); o[1] = f2bf(v0.y); o[2] = f2bf(v0.z); o[3] = f2bf(v0.w);
        o[4] = f2bf(v1.x); o[5] = f2bf(v1.y); o[6] = f2bf(v1.z); o[7] = f2bf(v1.w);
    } else {
        o = (u16x8){0, 0, 0, 0, 0, 0, 0, 0};
    }
    *(u16x8*)(out + (size_t)g * 8) = o;
}

// ---------------------------------------------------------------------------
// Transpose + convert: in f32 [R][C] -> out bf16 [C][R]. R,C % 32 == 0.
// ---------------------------------------------------------------------------
__global__ __launch_bounds__(256) void transpose_cvt(const float* __restrict__ in,
                                                     unsigned short* __restrict__ out,
                                                     int R, int C) {
    __shared__ float t[32][33];
    const int tx = threadIdx.x & 31, ty = threadIdx.x >> 5;   // ty 0..7
    const int r0 = blockIdx.y * 32, c0 = blockIdx.x * 32;
#pragma unroll
    for (int i = 0; i < 32; i += 8)
        t[ty + i][tx] = in[(size_t)(r0 + ty + i) * C + c0 + tx];
    __syncthreads();
#pragma unroll
    for (int i = 0; i < 32; i += 8)
        out[(size_t)(c0 + ty + i) * R + r0 + tx] = f2bf(t[tx][ty + i]);
}

// ---------------------------------------------------------------------------
// Convert rel tables (63x64 f32) -> bf16 with a zeroed 64th row.
// ---------------------------------------------------------------------------
__global__ __launch_bounds__(256) void cvt_tab(const float* __restrict__ a,
                                               const float* __restrict__ b,
                                               unsigned short* __restrict__ oa,
                                               unsigned short* __restrict__ ob) {
    const int i = blockIdx.x * 256 + threadIdx.x;   // 0..4095
    if (i < 4096) {
        oa[i] = (i < 63 * 64) ? f2bf(a[i]) : (unsigned short)0;
        ob[i] = (i < 63 * 64) ? f2bf(b[i]) : (unsigned short)0;
    }
}

// ---------------------------------------------------------------------------
// 256x256 bf16 GEMM, BK=32, 4-buffer counted-vmcnt pipeline (unchanged).
// ---------------------------------------------------------------------------
__global__ __launch_bounds__(512, 2) void gemm256_bf16(
    const unsigned short* __restrict__ A,
    const unsigned short* __restrict__ Bt,
    unsigned short* __restrict__ C,
    int M) {
    __shared__ short lds[4][2][8192];   // [buf][A/B][p*64 + b'*8 + s]
    const int tid = threadIdx.x, w = tid >> 6, lane = tid & 63;
    const int frow = lane & 15;

    const unsigned nwg = gridDim.x * gridDim.y;
    const unsigned lin = blockIdx.y * gridDim.x + blockIdx.x;
    const unsigned qq = nwg >> 3, rr = nwg & 7;
    const unsigned xcd = lin & 7, off = lin >> 3;
    const unsigned lin2 = (xcd < rr ? xcd * (qq + 1) : rr * (qq + 1) + (xcd - rr) * qq) + off;
    const int bx = lin2 % gridDim.x, by = lin2 / gridDim.x;
    const int bm = by * 256, bn = bx * 256;

    const int wm = w >> 2, wn = w & 3;

    const int p0s = w * 8 + (lane >> 3);
    const int bA = (lane & 7) ^ (p0s & 7);
    const int r0s = 2 * p0s + (bA >> 2);
    const int cbs = bA & 3;
    const unsigned short* aSrc = A + (size_t)(bm + r0s) * 768 + cbs * 8;
    const unsigned short* bSrc = Bt + (size_t)(bn + r0s) * 768 + cbs * 8;

#define STAGE256(buf_, t_) do {                                               \
    const unsigned short* a_ = aSrc + (size_t)(t_) * 32;                      \
    const unsigned short* b_ = bSrc + (size_t)(t_) * 32;                      \
    GLDS(a_,             &lds[buf_][0][w * 512]);                             \
    GLDS(a_ + 128 * 768, &lds[buf_][0][w * 512 + 4096]);                      \
    GLDS(b_,             &lds[buf_][1][w * 512]);                             \
    GLDS(b_ + 128 * 768, &lds[buf_][1][w * 512 + 4096]);                      \
} while (0)

    f32x4 acc[8][4];
#pragma unroll
    for (int m = 0; m < 8; ++m)
#pragma unroll
        for (int n = 0; n < 4; ++n) acc[m][n] = (f32x4){0.f, 0.f, 0.f, 0.f};

    const int bp = (((frow & 1) << 2) | (lane >> 4)) ^ (frow >> 1);
    const int pA0 = wm * 64 + (frow >> 1);
    const int pB0 = wn * 32 + (frow >> 1);

    STAGE256(0, 0);
    STAGE256(1, 1);
    asm volatile("s_waitcnt vmcnt(4)" ::: "memory");
    __builtin_amdgcn_s_barrier();

    for (int t = 0; t < 24; ++t) {
        const int cur = t & 3;
        s16x8 af[8], bf[4];
#pragma unroll
        for (int i = 0; i < 8; ++i)
            af[i] = *(const s16x8*)&lds[cur][0][(pA0 + i * 8) * 64 + bp * 8];
#pragma unroll
        for (int i = 0; i < 4; ++i)
            bf[i] = *(const s16x8*)&lds[cur][1][(pB0 + i * 8) * 64 + bp * 8];
        if (t + 2 < 24) STAGE256((t + 2) & 3, t + 2);
        asm volatile("s_waitcnt lgkmcnt(0)" ::: "memory");
        __builtin_amdgcn_sched_barrier(0);
        __builtin_amdgcn_s_setprio(1);
#pragma unroll
        for (int i = 0; i < 8; ++i)
#pragma unroll
            for (int nf = 0; nf < 4; ++nf)
                acc[i][nf] = __builtin_amdgcn_mfma_f32_16x16x32_bf16(
                    bf[nf], af[i], acc[i][nf], 0, 0, 0);
        __builtin_amdgcn_s_setprio(0);
        __builtin_amdgcn_sched_barrier(0);
        if (t == 22) asm volatile("s_waitcnt vmcnt(0)" ::: "memory");
        else         asm volatile("s_waitcnt vmcnt(4)" ::: "memory");
        __builtin_amdgcn_s_barrier();
    }
#undef STAGE256

    const int mrow0 = bm + wm * 128 + frow;
    const int cb0 = bn + wn * 64 + (lane >> 4) * 4;
#pragma unroll
    for (int m = 0; m < 8; ++m) {
        const int row = mrow0 + m * 16;
        if (row >= M) continue;
#pragma unroll
        for (int n = 0; n < 4; ++n) {
            const int col = cb0 + n * 16;
            const f32x4 v = acc[m][n];
            unsigned int lo = f2bf(v[0]) | ((unsigned int)f2bf(v[1]) << 16);
            unsigned int hi = f2bf(v[2]) | ((unsigned int)f2bf(v[3]) << 16);
            *(uint2*)&C[(size_t)row * 2304 + col] = make_uint2(lo, hi);
        }
    }
}

// ---------------------------------------------------------------------------
// bf16 MFMA GEMM (128² 2-phase) — used for the small proj GEMM.
// ---------------------------------------------------------------------------
static __device__ inline void stage_tiles(const unsigned short* aG,
                                          const unsigned short* bG,
                                          short* aL, short* bL, int w, int K) {
    short* a = aL + w * 1024;
    short* b = bL + w * 1024;
    GLDS(aG, a); GLDS(aG + 16 * (size_t)K, a + 512);
    GLDS(bG, b); GLDS(bG + 16 * (size_t)K, b + 512);
}

static __device__ inline void compute_tile(const short* As_, const short* Bs_,
                                           int ar, int br, int ko,
                                           f32x4 acc[4][4]) {
    s16x8 af[4], bf[4];
#pragma unroll
    for (int m = 0; m < 4; ++m)
        af[m] = *(const s16x8*)&As_[(ar + m * 16) * 32 + ko];
#pragma unroll
    for (int n = 0; n < 4; ++n)
        bf[n] = *(const s16x8*)&Bs_[(br + n * 16) * 32 + ko];
#pragma unroll
    for (int m = 0; m < 4; ++m)
#pragma unroll
        for (int n = 0; n < 4; ++n)
            acc[m][n] = __builtin_amdgcn_mfma_f32_16x16x32_bf16(bf[n], af[m], acc[m][n], 0, 0, 0);
}

__global__ __launch_bounds__(256) void gemm_bf16(const unsigned short* __restrict__ A,
                                                 const unsigned short* __restrict__ Bt,
                                                 const float* __restrict__ bias,
                                                 void* __restrict__ Cv,
                                                 int M, int N, int K, int out_bf) {
    __shared__ __align__(16) short As0[4096], Bs0[4096], As1[4096], Bs1[4096];
    const int tid = threadIdx.x;
    const int w = tid >> 6, lane = tid & 63;

    const unsigned nwg = gridDim.x * gridDim.y;
    const unsigned lin = blockIdx.y * gridDim.x + blockIdx.x;
    const unsigned qq = nwg >> 3, rr = nwg & 7;
    const unsigned xcd = lin & 7, off = lin >> 3;
    const unsigned lin2 = (xcd < rr ? xcd * (qq + 1) : rr * (qq + 1) + (xcd - rr) * qq) + off;
    const int bx = lin2 % gridDim.x, by = lin2 / gridDim.x;
    const int bm = by * 128, bn = bx * 128;

    const int sr = lane >> 2, sc8 = (lane & 3) * 8;
    const unsigned short* aG = A + (size_t)(bm + w * 32 + sr) * K + sc8;
    const unsigned short* bG = Bt + (size_t)(bn + w * 32 + sr) * K + sc8;

    f32x4 acc[4][4];
#pragma unroll
    for (int m = 0; m < 4; ++m)
#pragma unroll
        for (int n = 0; n < 4; ++n) acc[m][n] = (f32x4){0.f, 0.f, 0.f, 0.f};

    const int wr = w >> 1, wc = w & 1;
    const int ar = wr * 64 + (lane & 15);
    const int br = wc * 64 + (lane & 15);
    const int ko = (lane >> 4) * 8;

    stage_tiles(aG, bG, As0, Bs0, w, K);
    aG += 32; bG += 32;
    const int T = K >> 5;
    for (int t = 0; t < T; ++t) {
        __syncthreads();
        const bool last = (t + 1 == T);
        if ((t & 1) == 0) {
            if (!last) { stage_tiles(aG, bG, As1, Bs1, w, K); aG += 32; bG += 32; }
            compute_tile(As0, Bs0, ar, br, ko, acc);
        } else {
            if (!last) { stage_tiles(aG, bG, As0, Bs0, w, K); aG += 32; bG += 32; }
            compute_tile(As1, Bs1, ar, br, ko, acc);
        }
    }

    const int mrow0 = bm + wr * 64 + (lane & 15);
    const int cb0 = bn + wc * 64 + (lane >> 4) * 4;
    if (out_bf) {
        unsigned short* C = (unsigned short*)Cv;
#pragma unroll
        for (int m = 0; m < 4; ++m) {
            const int row = mrow0 + m * 16;
            if (row >= M) continue;
#pragma unroll
            for (int n = 0; n < 4; ++n) {
                const int col = cb0 + n * 16;
                const f32x4 v = acc[m][n];
                unsigned int lo = f2bf(v[0]) | ((unsigned int)f2bf(v[1]) << 16);
                unsigned int hi = f2bf(v[2]) | ((unsigned int)f2bf(v[3]) << 16);
                *(uint2*)&C[(size_t)row * N + col] = make_uint2(lo, hi);
            }
        }
    } else {
        float* C = (float*)Cv;
        f32x4 bv[4];
#pragma unroll
        for (int n = 0; n < 4; ++n)
            bv[n] = bias ? *(const f32x4*)(bias + cb0 + n * 16)
                         : (f32x4){0.f, 0.f, 0.f, 0.f};
#pragma unroll
        for (int m = 0; m < 4; ++m) {
            const int row = mrow0 + m * 16;
            if (row >= M) continue;
#pragma unroll
            for (int n = 0; n < 4; ++n) {
                const int col = cb0 + n * 16;
                f32x4 v = acc[m][n] + bv[n];
                *(f32x4*)&C[(size_t)row * N + col] = v;
            }
        }
    }
}

// ---------------------------------------------------------------------------
// Pool v2 (vectorized, restored): 192 threads/block, thread owns 4 channels.
// V^T stored f16 (PV uses the f16 MFMA).
// ---------------------------------------------------------------------------
__global__ __launch_bounds__(192) void pool_ln_kernel(
    const unsigned short* __restrict__ qkv,
    const float* __restrict__ dwq, const float* __restrict__ dwk, const float* __restrict__ dwv,
    const float* __restrict__ gq, const float* __restrict__ bq,
    const float* __restrict__ gk, const float* __restrict__ bk,
    const float* __restrict__ gv, const float* __restrict__ bv,
    float* __restrict__ qp, unsigned short* __restrict__ qbf,
    unsigned short* __restrict__ kbf, unsigned short* __restrict__ vtf16) {
    const int pos = blockIdx.x;          // 0..1023 spatial, 1024 = cls
    const int which = blockIdx.y;        // 0=q,1=k,2=v
    const int bi = blockIdx.z;
    const float* wt  = which == 0 ? dwq : which == 1 ? dwk : dwv;
    const float* gam = which == 0 ? gq  : which == 1 ? gk  : gv;
    const float* bet = which == 0 ? bq  : which == 1 ? bk  : bv;
    const int tid = threadIdx.x;
    const int d0 = tid * 4;
    const int db = d0 >> 6, ci0 = d0 & 63;
    const size_t base = (size_t)bi * NTOK * 2304 + (size_t)which * DIMC;

    float v0, v1, v2, v3;
    if (pos == 1024) {
        v0 = bf2f(qkv[base + d0]);     v1 = bf2f(qkv[base + d0 + 1]);
        v2 = bf2f(qkv[base + d0 + 2]); v3 = bf2f(qkv[base + d0 + 3]);
    } else {
        const int oh = pos >> 5, ow = pos & 31;
        float a0 = 0.f, a1 = 0.f, a2 = 0.f, a3 = 0.f;
#pragma unroll
        for (int kh = 0; kh < 3; ++kh) {
            const int ih = oh * 2 + kh;             // pad_lo = 0
            if (ih >= 64) continue;
#pragma unroll
            for (int kw = 0; kw < 3; ++kw) {
                const int iw = ow * 2 + kw;
                if (iw >= 64) continue;
                const int pix = ih * 64 + iw;
                const int t6 = pix * 12 + db;
                const int l = t6 & 4095, hin = t6 >> 12;
                const ushort4 pv = *(const ushort4*)(qkv + base + (size_t)(1 + l) * 2304 + hin * 64 + ci0);
                const f32x4 wv = *(const f32x4*)(wt + (kh * 3 + kw) * DIMC + d0);
                a0 += bf2f(pv.x) * wv[0];
                a1 += bf2f(pv.y) * wv[1];
                a2 += bf2f(pv.z) * wv[2];
                a3 += bf2f(pv.w) * wv[3];
            }
        }
        v0 = a0; v1 = a1; v2 = a2; v3 = a3;
    }

    float s = v0 + v1 + v2 + v3;
#pragma unroll
    for (int o = 8; o > 0; o >>= 1) s += __shfl_xor(s, o);
    const float mu = s * (1.f / 64.f);
    const float e0 = v0 - mu, e1 = v1 - mu, e2 = v2 - mu, e3 = v3 - mu;
    float s2 = e0 * e0 + e1 * e1 + e2 * e2 + e3 * e3;
#pragma unroll
    for (int o = 8; o > 0; o >>= 1) s2 += __shfl_xor(s2, o);
    const float inv = rsqrtf(s2 * (1.f / 64.f) + 1e-3f);
    const f32x4 gv4 = *(const f32x4*)(gam + ci0);
    const f32x4 bv4 = *(const f32x4*)(bet + ci0);
    f32x4 res;
    res[0] = e0 * inv * gv4[0] + bv4[0];
    res[1] = e1 * inv * gv4[1] + bv4[1];
    res[2] = e2 * inv * gv4[2] + bv4[2];
    res[3] = e3 * inv * gv4[3] + bv4[3];

    int h, tok;
    if (pos == 1024) { h = db; tok = 0; }
    else { const int idx = pos * 12 + db; h = idx >> 10; tok = 1 + (idx & 1023); }
    const size_t bh = (size_t)(bi * 12 + h);
    if (which == 0) {
        const unsigned int lo = f2bf(res[0]) | ((unsigned int)f2bf(res[1]) << 16);
        const unsigned int hi = f2bf(res[2]) | ((unsigned int)f2bf(res[3]) << 16);
        *(f32x4*)&qp[(bh * NPOOL + tok) * 64 + ci0] = res;
        *(uint2*)&qbf[(bh * 1040 + tok) * 64 + ci0] = make_uint2(lo, hi);
    } else if (which == 1) {
        const unsigned int lo = f2bf(res[0]) | ((unsigned int)f2bf(res[1]) << 16);
        const unsigned int hi = f2bf(res[2]) | ((unsigned int)f2bf(res[3]) << 16);
        *(uint2*)&kbf[(bh * 1056 + tok) * 64 + ci0] = make_uint2(lo, hi);
    } else {
#pragma unroll
        for (int j = 0; j < 4; ++j)
            vtf16[(bh * 64 + ci0 + j) * 1056 + tok] = f2h(res[j]);
    }
}

// ---------------------------------------------------------------------------
// rel via MFMA. Block = (4 qh, bh); wave w owns qh = bx*4+w. For fixed qh:
// relH[qw][j] = q[qw]·rph[qh-j+31]  -> straight 32x32 GEMM over K=64 (8 mfma)
// relW[qw][j] = q[qw]·rpw[qw-j+31]  -> full correlation C[qw][u]=Q·rpw^T
//   (16 mfma over u=0..63, row 63 zero) then gather j=qw-u+31.
// ---------------------------------------------------------------------------
__global__ __launch_bounds__(256) void rel_mfma(
    const unsigned short* __restrict__ qbf,
    const unsigned short* __restrict__ rphb,
    const unsigned short* __restrict__ rpwb,
    float* __restrict__ relH, float* __restrict__ relW) {
    const int tid = threadIdx.x, w = tid >> 6, lane = tid & 63;
    const int qh = blockIdx.x * 4 + w;     // 0..31
    const int bh = blockIdx.y;             // 0..47
    const int frow = lane & 15, fcol = (lane >> 4) * 8;
    const int s0 = (lane >> 4) * 4;

    s16x8 aq[2][2];
#pragma unroll
    for (int t = 0; t < 2; ++t) {
        const unsigned short* p = qbf + ((size_t)bh * 1040 + 1 + qh * 32 + t * 16 + frow) * 64 + fcol;
        aq[t][0] = *(const s16x8*)p;
        aq[t][1] = *(const s16x8*)(p + 32);
    }

    // relH: B rows = rph[qh+31-j], j = jt*16+frow
#pragma unroll
    for (int jt = 0; jt < 2; ++jt) {
        const int u = qh + 31 - (jt * 16 + frow);
        const unsigned short* bp = rphb + u * 64 + fcol;
        s16x8 b0 = *(const s16x8*)bp;
        s16x8 b1 = *(const s16x8*)(bp + 32);
#pragma unroll
        for (int t = 0; t < 2; ++t) {
            f32x4 s = (f32x4){0.f, 0.f, 0.f, 0.f};
            s = __builtin_amdgcn_mfma_f32_16x16x32_bf16(b0, aq[t][0], s, 0, 0, 0);
            s = __builtin_amdgcn_mfma_f32_16x16x32_bf16(b1, aq[t][1], s, 0, 0, 0);
            const int qw = t * 16 + frow;
            *(f32x4*)&relH[((size_t)bh * 1024 + qh * 32 + qw) * 32 + jt * 16 + s0] = s;
        }
    }

    // relW: B rows = rpw[u], u = ut*16+frow; gather j = qw-u+31
#pragma unroll
    for (int ut = 0; ut < 4; ++ut) {
        const unsigned short* bp = rpwb + (ut * 16 + frow) * 64 + fcol;
        s16x8 b0 = *(const s16x8*)bp;
        s16x8 b1 = *(const s16x8*)(bp + 32);
#pragma unroll
        for (int t = 0; t < 2; ++t) {
            f32x4 s = (f32x4){0.f, 0.f, 0.f, 0.f};
            s = __builtin_amdgcn_mfma_f32_16x16x32_bf16(b0, aq[t][0], s, 0, 0, 0);
            s = __builtin_amdgcn_mfma_f32_16x16x32_bf16(b1, aq[t][1], s, 0, 0, 0);
            const int qw = t * 16 + frow;
#pragma unroll
            for (int r = 0; r < 4; ++r) {
                const int u = ut * 16 + s0 + r;
                const int j = qw - u + 31;
                if ((unsigned)j < 32u)
                    relW[((size_t)bh * 1024 + qh * 32 + qw) * 32 + j] = s[r];
            }
        }
    }
}

// ---------------------------------------------------------------------------
// MFMA attention, 8 waves, f16 logits/P tile (45 KB LDS, 3 blocks/CU).
// (round-13 version: fused-max pass1)
// ---------------------------------------------------------------------------
#define LSTR16 1088
#define LI16(q, k) ((q) * LSTR16 + (((((k) >> 3) ^ ((q) & 7)) << 3) | ((k) & 7)))
__global__ __launch_bounds__(512) void attn_mfma(
    const unsigned short* __restrict__ qbf, const unsigned short* __restrict__ kbf,
    const unsigned short* __restrict__ vtf16, const float* __restrict__ qpf,
    const float* __restrict__ relH, const float* __restrict__ relW,
    unsigned short* __restrict__ outbf) {
    __shared__ __align__(16) unsigned short logits_s[16 * LSTR16];
    __shared__ float relh_s[32][17];
    __shared__ float relw_s[32][17];
    __shared__ __align__(16) float partial_s[4][16][20];
    __shared__ float srow_s[16];
    __shared__ float wmax_s[8][16];
    const int bh = blockIdx.y, bi = bh / 12, hh = bh % 12;
    const int q0 = blockIdx.x * 16;
    const int tid = threadIdx.x, w = tid >> 6, lane = tid & 63;

    {
        const int qi = tid >> 5, j = tid & 31;
        const int qg = q0 + qi;
        float rh = 0.f, rw = 0.f;
        if (qg >= 1 && qg < NPOOL) {
            const size_t rb = ((size_t)bh * 1024 + (qg - 1)) * 32;
            rh = relH[rb + j]; rw = relW[rb + j];
        }
        relh_s[j][qi] = rh; relw_s[j][qi] = rw;
    }

    const int frow = lane & 15, fcol = (lane >> 4) * 8;
    const unsigned short* qrow_p = qbf + ((size_t)bh * 1040 + q0 + frow) * 64 + fcol;
    s16x8 aq0 = *(const s16x8*)qrow_p;
    s16x8 aq1 = *(const s16x8*)(qrow_p + 32);
    __syncthreads();

    // ---- pass 1: logits -> f16 tile, fused per-lane max ----
    const int qrow1 = frow, qg1 = q0 + qrow1;
    float lmax = -3.0e38f;
    for (int t = w; t < 66; t += 8) {
        const int k0 = t * 16;
        const unsigned short* kb = kbf + ((size_t)bh * 1056 + k0 + frow) * 64 + fcol;
        s16x8 b0 = *(const s16x8*)kb;
        s16x8 b1 = *(const s16x8*)(kb + 32);
        f32x4 s = (f32x4){0.f, 0.f, 0.f, 0.f};
        s = __builtin_amdgcn_mfma_f32_16x16x32_bf16(b0, aq0, s, 0, 0, 0);
        s = __builtin_amdgcn_mfma_f32_16x16x32_bf16(b1, aq1, s, 0, 0, 0);
        const int kbase = k0 + (lane >> 4) * 4;
        unsigned short hv[4];
#pragma unroll
        for (int r = 0; r < 4; ++r) {
            const int kcol = kbase + r;
            float v;
            if (kcol >= NPOOL) {
                v = -60000.0f;                        // f16-representable mask
            } else {
                v = s[r] * 0.125f;
                if (kcol >= 1 && qg1 >= 1)
                    v += relh_s[(kcol - 1) >> 5][qrow1] + relw_s[(kcol - 1) & 31][qrow1];
            }
            lmax = fmaxf(lmax, v);
            hv[r] = f2h(v);
        }
        const unsigned int lo = hv[0] | ((unsigned int)hv[1] << 16);
        const unsigned int hi = hv[2] | ((unsigned int)hv[3] << 16);
        *(uint2*)&logits_s[LI16(qrow1, kbase)] = make_uint2(lo, hi);
    }
    lmax = fmaxf(lmax, __shfl_xor(lmax, 16));
    lmax = fmaxf(lmax, __shfl_xor(lmax, 32));
    if (lane < 16) wmax_s[w][frow] = lmax;
    __syncthreads();

    // ---- pass 2: exp + sum in place (row max from wmax_s) ----
    for (int qi = w; qi < 16; qi += 8) {
        float m = wmax_s[0][qi];
#pragma unroll
        for (int w2 = 1; w2 < 8; ++w2) m = fmaxf(m, wmax_s[w2][qi]);
        float sum = 0.f;
#pragma unroll
        for (int i = 0; i < 9; ++i) {
            const int k = i * 128 + 2 * lane;
            if (k < 1056) {
                unsigned int* p = (unsigned int*)&logits_s[LI16(qi, k)];
                const unsigned int v = *p;
                const float p0 = __expf(h2f((unsigned short)v) - m);
                const float p1 = __expf(h2f((unsigned short)(v >> 16)) - m);
                *p = f2h(p0) | ((unsigned int)f2h(p1) << 16);
                sum += p0 + p1;
            }
        }
#pragma unroll
        for (int o = 32; o > 0; o >>= 1) sum += __shfl_xor(sum, o);
        if (lane == 0) srow_s[qi] = sum;
    }
    __syncthreads();

    // ---- pass 3: PV via f16 mfma, split (d-frag f) x (k-half h) ----
    const int f = w & 3, h = w >> 2;
    const int cstart = h ? 17 : 0, cend = h ? 33 : 17;
    const unsigned short* vrow = vtf16 + ((size_t)bh * 64 + f * 16 + frow) * 1056 + fcol;
    f32x4 acc = (f32x4){0.f, 0.f, 0.f, 0.f};
    for (int c = cstart; c < cend; ++c) {
        const int kb0 = c * 32 + fcol;
        f16x8 pa = *(const f16x8*)&logits_s[LI16(frow, kb0)];
        f16x8 vb = *(const f16x8*)(vrow + c * 32);
        acc = __builtin_amdgcn_mfma_f32_16x16x32_f16(vb, pa, acc, 0, 0, 0);
    }
    const int qrow = frow, qg = q0 + qrow;
    const int s0 = (lane >> 4) * 4;
    if (h == 1) {
        *(f32x4*)&partial_s[f][qrow][s0] = acc;
    }
    __syncthreads();
    if (h == 0 && qg < NPOOL) {
        const f32x4 other = *(const f32x4*)&partial_s[f][qrow][s0];
        const int d0 = f * 16 + s0;
        const float inv = 1.f / srow_s[qrow];
        const f32x4 res = *(const f32x4*)&qpf[((size_t)bh * NPOOL + qg) * 64 + d0];
        f32x4 o;
#pragma unroll
        for (int r = 0; r < 4; ++r) o[r] = (acc[r] + other[r]) * inv + res[r];
        const unsigned int lo = f2bf(o[0]) | ((unsigned int)f2bf(o[1]) << 16);
        const unsigned int hi = f2bf(o[2]) | ((unsigned int)f2bf(o[3]) << 16);
        *(uint2*)&outbf[((size_t)bi * NPOOL + qg) * DIMC + hh * 64 + d0] = make_uint2(lo, hi);
    }
}

// ---------------------------------------------------------------------------
extern "C" void kernel_launch(void* const* d_in, const int* in_sizes, int n_in,
                              void* d_out, int out_size, void* d_ws, size_t ws_size,
                              hipStream_t stream) {
    const float* x     = (const float*)d_in[0];
    const float* wqkv  = (const float*)d_in[1];
    const float* dwq   = (const float*)d_in[2];
    const float* dwk   = (const float*)d_in[3];
    const float* dwv   = (const float*)d_in[4];
    const float* gq    = (const float*)d_in[5];
    const float* bq    = (const float*)d_in[6];
    const float* gk    = (const float*)d_in[7];
    const float* bk    = (const float*)d_in[8];
    const float* gv    = (const float*)d_in[9];
    const float* bv    = (const float*)d_in[10];
    const float* rph   = (const float*)d_in[11];
    const float* rpw   = (const float*)d_in[12];
    const float* wproj = (const float*)d_in[13];
    const float* bproj = (const float*)d_in[14];
    float* out = (float*)d_out;
    float* ws_f = (float*)d_ws;

    // Workspace layout (f32 units): same as round 9/10, plus bf16 rel tables
    // at the tail of the A-region (A+8,875,008 .. A+8,879,104).
    const size_t A = 37757952;
    unsigned short* qkv_bf = (unsigned short*)ws_f;
    float* qp = ws_f + A;
    unsigned short* qp_bf = (unsigned short*)(ws_f + A + 3148800);
    unsigned short* kp_bf = (unsigned short*)(ws_f + A + 4746240);
    unsigned short* vt_f16 = (unsigned short*)(ws_f + A + 6368256);
    unsigned short* wqkv_bf = (unsigned short*)(ws_f + A + 7990272);
    unsigned short* rph_bf = (unsigned short*)(ws_f + A + 8875008);   // 64x64 u16
    unsigned short* rpw_bf = (unsigned short*)(ws_f + A + 8877056);   // 64x64 u16
    unsigned short* x_bf = (unsigned short*)qp;
    float* relH   = ws_f;
    float* relW   = ws_f + 1572864;
    unsigned short* outpre_bf = (unsigned short*)(ws_f + 3145728);  // 4224x768 u16
    unsigned short* wproj_bf  = (unsigned short*)(ws_f + 7916544);

    // 0) rel tables -> bf16 (row 63 zeroed)
    cvt_tab<<<16, 256, 0, stream>>>(rph, rpw, rph_bf, rpw_bf);
    // 1) convert + pad A (to 16640 rows), transpose + convert B for qkv GEMM
    cvt_pad<<<(16640 * 96 + 255) / 256, 256, 0, stream>>>(x, x_bf, 16388, 16640 * 96);
    transpose_cvt<<<dim3(2304 / 32, 768 / 32), 256, 0, stream>>>(wqkv, wqkv_bf, 768, 2304);
    // 2) QKV GEMM (256², BK=32, 4-buffer counted-vmcnt) -> bf16
    gemm256_bf16<<<dim3(9, 65), 512, 0, stream>>>(x_bf, wqkv_bf, qkv_bf, 16388);
    // 3) conv-pool + LayerNorm (vectorized v2) -> qp f32, qp/kp bf16, V^T f16
    pool_ln_kernel<<<dim3(1025, 3, 4), 192, 0, stream>>>(qkv_bf, dwq, dwk, dwv,
                                                         gq, bq, gk, bk, gv, bv,
                                                         qp, qp_bf, kp_bf, vt_f16);
    // 4) rel_h / rel_w tables via MFMA
    rel_mfma<<<dim3(8, 48), 256, 0, stream>>>(qp_bf, rph_bf, rpw_bf, relH, relW);
    // 5) MFMA attention (8 waves, fused-max softmax) -> outpre_bf bf16
    attn_mfma<<<dim3(65, 48), 512, 0, stream>>>(qp_bf, kp_bf, vt_f16, qp, relH, relW, outpre_bf);
    // 6) proj GEMM (128² bf16 MFMA): (4100 x 768) @ (768 x 768) + bias -> f32
    transpose_cvt<<<dim3(768 / 32, 768 / 32), 256, 0, stream>>>(wproj, wproj_bf, 768, 768);
    gemm_bf16<<<dim3(6, 33), 256, 0, stream>>>(outpre_bf, wproj_bf, bproj, out, 4100, 768, 768, 0);
}